// Round 13
// baseline (270.953 us; speedup 1.0000x reference)
//
#include <hip/hip_runtime.h>

#define N_ 16384
#define D_ 256
#define LOG2E 1.4426950408889634f
#define HEXP2(x) __builtin_amdgcn_exp2f(x)

typedef __attribute__((ext_vector_type(8))) short short8;
typedef __attribute__((ext_vector_type(16))) float floatx16;

typedef __attribute__((address_space(1))) const unsigned int gu32_t;
typedef __attribute__((address_space(3))) unsigned int lu32_t;

__device__ __forceinline__ void async16(const void* g, void* l) {
  __builtin_amdgcn_global_load_lds((gu32_t*)g, (lu32_t*)l, 16, 0, 0);
}

__device__ __forceinline__ unsigned short f2bf(float x) {
  unsigned int u = __float_as_uint(x);
  u += 0x7fffu + ((u >> 16) & 1u);
  return (unsigned short)(u >> 16);
}

__device__ __forceinline__ float max3f(float a, float b, float c) {
  return fmaxf(fmaxf(a, b), c);  // clang folds to v_max3_f32
}

// ---------------- prep: fp32 -> bf16 packed (write-coalesced) + fused exact diag ----------------
// (passed rounds 1, 2, 5, 8, 10, 12)
__global__ void prep_pack(const float* __restrict__ img, const float* __restrict__ txt,
                          const float* __restrict__ ls, short* __restrict__ PA,
                          short* __restrict__ PB, float* __restrict__ diag2,
                          float* __restrict__ out) {
  const int tid = threadIdx.x;
  const int t = blockIdx.x * 1024 + tid;
  const int m = tid & 31, h = (tid >> 5) & 1, ks = (tid >> 6) & 15;
  const int G = blockIdx.x;
  const int row = G * 32 + m, col = ks * 16 + h * 8;
  const float s2 = ls[0] * LOG2E;
  const float4* sa = (const float4*)(img + (size_t)row * D_ + col);
  const float4* sb = (const float4*)(txt + (size_t)row * D_ + col);
  float4 a0 = sa[0], a1 = sa[1];
  float4 b0 = sb[0], b1 = sb[1];
  short8 oa, ob;
  oa[0] = (short)f2bf(a0.x * s2); oa[1] = (short)f2bf(a0.y * s2);
  oa[2] = (short)f2bf(a0.z * s2); oa[3] = (short)f2bf(a0.w * s2);
  oa[4] = (short)f2bf(a1.x * s2); oa[5] = (short)f2bf(a1.y * s2);
  oa[6] = (short)f2bf(a1.z * s2); oa[7] = (short)f2bf(a1.w * s2);
  ob[0] = (short)f2bf(b0.x); ob[1] = (short)f2bf(b0.y);
  ob[2] = (short)f2bf(b0.z); ob[3] = (short)f2bf(b0.w);
  ob[4] = (short)f2bf(b1.x); ob[5] = (short)f2bf(b1.y);
  ob[6] = (short)f2bf(b1.z); ob[7] = (short)f2bf(b1.w);
  ((short8*)PA)[t] = oa;
  ((short8*)PB)[t] = ob;

  float d = a0.x * b0.x + a0.y * b0.y + a0.z * b0.z + a0.w * b0.w
          + a1.x * b1.x + a1.y * b1.y + a1.z * b1.z + a1.w * b1.w;
  __shared__ float red[32][33];
  red[tid >> 5][m] = d;
  __syncthreads();
  if (tid < 32) {
    float s = 0.f;
    #pragma unroll
    for (int q = 0; q < 32; ++q) s += red[q][tid];
    diag2[G * 32 + tid] = s * s2;  // log2-domain scaled diagonal
  }
  if (t == 0) out[0] = 0.f;
}

// ---------------- gemm + stats: 4-buffer staging, single barrier per phase ----------------
// r12 base (gemm 167us) with ONE sync restructure, bisected:
//  * 4 staging buffers (buf = chunk&3), ONE barrier per phase: wait own vmcnt(4)
//    -> s_barrier -> compute -> issue chunk n+2 into buf (n+2)&3. Safety: at
//    barrier n every wave has finished compute n-1 >= n-2, the last reader of
//    buf (n+2)&3; per-wave vmcnt-before-barrier guarantees chunk n fully landed
//    (each wave vouches for its own slice). Same argument class as the r10-proven
//    closing-barrier removal. NOTE: r3's inf is attributed to its racc stats
//    bundle (r4 failed with 2-buffer staging restored) -- this round isolates the
//    staging for a clean verdict. Barriers/tile: 9 -> 5.
//  * Row path: twice-green (r6, r9 correctness) butterfly + rowbuf2[128][20]
//    (10KB) so 64KB staging fits: LDS 76KB -> still 2 blocks/CU.
// Kept from r12: zv first-MFMA (no acc zero-init), max3 tree, 4-chain sums,
// colbuf seal + pC merge, no closing barrier.
// GEOMETRY FIXED: 64x64 wave tiles. OCCUPANCY PINNED: 2 blocks/CU.
// BANNED (r2/r4/r6/r7/r9/r11): setprio; racc register rows + end transpose;
// colbuf double-buffer; per-wave-private staging; XCD swizzle; 3 waves/EU;
// 32x128 tiles.
__global__ __launch_bounds__(256, 2)
void gemm_stats(const short* __restrict__ PA, const short* __restrict__ PB,
                float2* __restrict__ pR, float2* __restrict__ pC) {
  __shared__ __align__(16) char smem[77824];
  // [0,65536): B staging 4 x 16KB (buf = chunk&3; 16 frags x 1KB each)
  // [65536,75776): rowbuf2 f32 [128 rows][stride 20] (srcs 0..15 used)
  // [75776,77824): colbuf float2[2 wr][128]
  float* rowbuf2 = (float*)(smem + 65536);
  float2* colbuf = (float2*)(smem + 75776);

  const int tid = threadIdx.x, lane = tid & 63, wv = tid >> 6;
  const int wr = wv >> 1, wc = wv & 1;
  const int m = lane & 31, h = lane >> 5;
  const int stripe = blockIdx.x, by = blockIdx.y;

  // ---- A panel into registers: rows stripe*128 + wr*64 .. +64, all K
  short8 areg[2][16];
  #pragma unroll
  for (int g = 0; g < 2; ++g)
    #pragma unroll
    for (int ks = 0; ks < 16; ++ks)
      areg[g][ks] = *(const short8*)(PA +
          ((size_t)((stripe * 4 + wr * 2 + g) * 16 + ks)) * 512 + lane * 8);
  asm volatile("s_waitcnt vmcnt(0)" ::: "memory");

  floatx16 acc[2][2];
  floatx16 zv;
  #pragma unroll
  for (int r = 0; r < 16; ++r) zv[r] = 0.f;

  // stage chunk (jj2, c2) -> buffer bufsel. Wave wv stages ks-slice wv for 4 ct frags.
  auto issue = [&](int jj2, int c2, int bufsel) {
    const short* base = PB + ((size_t)((by * 64 + jj2 * 4) * 16) + c2 * 4 + wv) * 512 + lane * 8;
    char* dst = smem + bufsel * 16384 + wv * 1024;
    #pragma unroll
    for (int ct = 0; ct < 4; ++ct)
      async16(base + (size_t)ct * 8192, dst + ct * 4096);
  };
  auto compute = [&](int c, int bufsel, bool first) {
    char* base = smem + bufsel * 16384 + lane * 16;
    #pragma unroll
    for (int ksl = 0; ksl < 4; ++ksl) {
      short8 b0 = *(const short8*)(base + ((wc * 2 + 0) * 4 + ksl) * 1024);
      short8 b1 = *(const short8*)(base + ((wc * 2 + 1) * 4 + ksl) * 1024);
      int ks = c * 4 + ksl;  // compile-time under unroll
      if (first && ksl == 0) {
        acc[0][0] = __builtin_amdgcn_mfma_f32_32x32x16_bf16(areg[0][ks], b0, zv, 0, 0, 0);
        acc[1][0] = __builtin_amdgcn_mfma_f32_32x32x16_bf16(areg[1][ks], b0, zv, 0, 0, 0);
        acc[0][1] = __builtin_amdgcn_mfma_f32_32x32x16_bf16(areg[0][ks], b1, zv, 0, 0, 0);
        acc[1][1] = __builtin_amdgcn_mfma_f32_32x32x16_bf16(areg[1][ks], b1, zv, 0, 0, 0);
      } else {
        acc[0][0] = __builtin_amdgcn_mfma_f32_32x32x16_bf16(areg[0][ks], b0, acc[0][0], 0, 0, 0);
        acc[1][0] = __builtin_amdgcn_mfma_f32_32x32x16_bf16(areg[1][ks], b0, acc[1][0], 0, 0, 0);
        acc[0][1] = __builtin_amdgcn_mfma_f32_32x32x16_bf16(areg[0][ks], b1, acc[0][1], 0, 0, 0);
        acc[1][1] = __builtin_amdgcn_mfma_f32_32x32x16_bf16(areg[1][ks], b1, acc[1][1], 0, 0, 0);
      }
    }
  };

  issue(0, 0, 0);  // chunk 0 -> buf 0
  issue(0, 1, 1);  // chunk 1 -> buf 1

  float Mr = -3.0e38f, Sr = 0.f;  // row LSE state: row = stripe*128 + wr*64 + wc*32 + m

  for (int jj = 0; jj < 16; ++jj) {
    #pragma unroll
    for (int c = 0; c < 4; ++c) {
      // chunk n = jj*4 + c lives in buf n&3 == c (compile-time)
      if (jj == 15 && c == 3) { asm volatile("s_waitcnt vmcnt(0)" ::: "memory"); }
      else                    { asm volatile("s_waitcnt vmcnt(4)" ::: "memory"); }
      __builtin_amdgcn_s_barrier();
      asm volatile("" ::: "memory");
      compute(c, c, c == 0);
      asm volatile("" ::: "memory");
      int nc = c + 2;
      int jj2 = jj + (nc >> 2);
      if (jj2 < 16) issue(jj2, nc & 3, nc & 3);
    }

    // ---- stats. acc[rt][ctl][reg]: row(in tile) = wr*64+rt*32+(reg&3)+8*(reg>>2)+4*h
    //                                col(in tile) = wc*64+ctl*32+m
    float vm[4];
    #pragma unroll
    for (int q = 0; q < 4; ++q) {
      const floatx16& a = acc[q >> 1][q & 1];
      float t0 = max3f(a[0],  a[1],  a[2]);
      float t1 = max3f(a[3],  a[4],  a[5]);
      float t2 = max3f(a[6],  a[7],  a[8]);
      float t3 = max3f(a[9],  a[10], a[11]);
      float t4 = max3f(a[12], a[13], a[14]);
      vm[q] = fmaxf(max3f(t0, t1, a[15]), max3f(t2, t3, t4));
    }
    float v = fmaxf(max3f(vm[0], vm[1], vm[2]), vm[3]);
    #pragma unroll
    for (int off = 1; off < 64; off <<= 1) v = fmaxf(v, __shfl_xor(v, off));
    float msub = v - 96.f;

    #pragma unroll
    for (int rt = 0; rt < 2; ++rt)
      #pragma unroll
      for (int ctl = 0; ctl < 2; ++ctl)
        #pragma unroll
        for (int r = 0; r < 16; ++r) acc[rt][ctl][r] = HEXP2(acc[rt][ctl][r] - msub);

    // col partials: sum over 64 rows of wave tile (reg-local + xor32)
    #pragma unroll
    for (int ctl = 0; ctl < 2; ++ctl) {
      float cp0 = 0.f, cp1 = 0.f;
      #pragma unroll
      for (int r = 0; r < 8; ++r) {
        cp0 += acc[0][ctl][r] + acc[1][ctl][r];
        cp1 += acc[0][ctl][r + 8] + acc[1][ctl][r + 8];
      }
      float cp = cp0 + cp1;
      cp += __shfl_xor(cp, 32);
      if (h == 0) colbuf[wr * 128 + wc * 64 + ctl * 32 + m] = make_float2(msub, cp);
    }

    // row partials (r6/r9-proven): ctl-add, butterfly xor 8/16 (lane group m&7
    // holds the 8-col partial), lanes m in [rt*8,rt*8+8) write src wc*8+(m&7).
    float rp[2][16];
    #pragma unroll
    for (int rt = 0; rt < 2; ++rt)
      #pragma unroll
      for (int r = 0; r < 16; ++r) {
        float x = acc[rt][0][r] + acc[rt][1][r];
        x += __shfl_xor(x, 8);
        x += __shfl_xor(x, 16);
        rp[rt][r] = x;
      }
    #pragma unroll
    for (int rt = 0; rt < 2; ++rt)
      #pragma unroll
      for (int r = 0; r < 16; ++r)
        if ((m >> 3) == rt)
          rowbuf2[(size_t)(wr * 64 + rt * 32 + (r & 3) + 8 * (r >> 2) + 4 * h) * 20 +
                  wc * 8 + (m & 7)] = rp[rt][r];

    asm volatile("s_waitcnt lgkmcnt(0)" ::: "memory");
    __builtin_amdgcn_s_barrier();
    asm volatile("" ::: "memory");

    // phase2 rows: own row = wr*64 + wc*32 + m; sum 16 srcs (h-redundant)
    {
      const float* rb = rowbuf2 + (size_t)(wr * 64 + wc * 32 + m) * 20;
      float4 q0 = *(const float4*)(rb + 0);
      float4 q1 = *(const float4*)(rb + 4);
      float4 q2 = *(const float4*)(rb + 8);
      float4 q3 = *(const float4*)(rb + 12);
      float s = ((q0.x + q0.y) + (q0.z + q0.w)) + ((q1.x + q1.y) + (q1.z + q1.w))
              + ((q2.x + q2.y) + (q2.z + q2.w)) + ((q3.x + q3.y) + (q3.z + q3.w));
      if (s > 0.f) {
        if (msub > Mr) { Sr = Sr * HEXP2(Mr - msub) + s; Mr = msub; }
        else           { Sr += s * HEXP2(msub - Mr); }
      }
    }
    // phase2 cols: merge wr=0/1 partials -> pC
    if (tid < 128) {
      float2 c0 = colbuf[tid], c1 = colbuf[128 + tid];
      float M = -3.0e38f, L = 0.f;
      if (c0.y > 0.f) { M = c0.x; L = c0.y; }
      if (c1.y > 0.f) {
        if (c1.x > M) { L = L * HEXP2(M - c1.x) + c1.y; M = c1.x; }
        else          { L += c1.y * HEXP2(c1.x - M); }
      }
      pC[(size_t)stripe * N_ + by * 2048 + jj * 128 + tid] = make_float2(M, L);
    }
    // (no closing barrier: next rowbuf2/colbuf writes are behind tile jj+1's
    //  4 phase barriers -- r10-proven subsumption class)
  }

  if (h == 0)
    pR[(size_t)by * N_ + stripe * 128 + wr * 64 + wc * 32 + m] = make_float2(Mr, Sr);
}

// ---------------- merge v2: parallelized (passed rounds 8, 10, 12) ----------------
__global__ void merge_kernel(const float2* __restrict__ pR, const float2* __restrict__ pC,
                             const float* __restrict__ diag2, float* __restrict__ out) {
  auto mrg = [](float& M, float& L, float2 w) {
    if (w.y > 0.f) {
      if (w.x > M) { L = L * exp2f(M - w.x) + w.y; M = w.x; }
      else         { L += w.y * exp2f(w.x - M); }
    }
  };
  const int b = blockIdx.x, tid = threadIdx.x;
  float val = 0.f;

  if (b < 64) {
    int i = b * 256 + tid;
    float M = -3.0e38f, L = 0.f;
    #pragma unroll
    for (int g = 0; g < 8; ++g) mrg(M, L, pR[(size_t)g * N_ + i]);
    val = (M + log2f(fmaxf(L, 1e-45f))) - diag2[i];
  } else {
    int cb = b - 64;                 // 0..511
    int i = cb * 32 + (tid & 31);
    int s0 = (tid >> 5) * 16;
    float M = -3.0e38f, L = 0.f;
    #pragma unroll
    for (int k = 0; k < 16; ++k) mrg(M, L, pC[(size_t)(s0 + k) * N_ + i]);
    __shared__ float2 part[8][32];
    part[tid >> 5][tid & 31] = make_float2(M, L);
    __syncthreads();
    if (tid < 32) {
      float M2 = -3.0e38f, L2 = 0.f;
      #pragma unroll
      for (int q = 0; q < 8; ++q) mrg(M2, L2, part[q][tid]);
      val = (M2 + log2f(fmaxf(L2, 1e-45f))) - diag2[cb * 32 + tid];
    }
  }

  __shared__ float red[256];
  red[tid] = val;
  __syncthreads();
  #pragma unroll
  for (int s = 128; s > 0; s >>= 1) {
    if (tid < s) red[tid] += red[tid + s];
    __syncthreads();
  }
  if (tid == 0)
    atomicAdd(out, red[0] * (0.69314718055994531f / 32768.0f));  // ln2 / (2N)
}

// ---------------- launch ----------------
extern "C" void kernel_launch(void* const* d_in, const int* in_sizes, int n_in,
                              void* d_out, int out_size, void* d_ws, size_t ws_size,
                              hipStream_t stream) {
  const float* img = (const float*)d_in[0];
  const float* txt = (const float*)d_in[1];
  const float* ls  = (const float*)d_in[2];
  float* out = (float*)d_out;

  char* ws = (char*)d_ws;
  short* PA    = (short*)(ws);                 //  8 MB
  short* PB    = (short*)(ws + 8388608);       //  8 MB
  float* diag2 = (float*)(ws + 16777216);      //  64 KB
  float2* pR   = (float2*)(ws + 16843008);     //  1 MB  (8 x N)
  float2* pC   = (float2*)(ws + 17891584);     //  16 MB (128 x N)

  hipLaunchKernelGGL(prep_pack, dim3(512), dim3(1024), 0, stream, img, txt, ls, PA, PB, diag2, out);
  hipLaunchKernelGGL(gemm_stats, dim3(128, 8), dim3(256), 0, stream, PA, PB, pR, pC);
  hipLaunchKernelGGL(merge_kernel, dim3(576), dim3(256), 0, stream, pR, pC, diag2, out);
}

// Round 14
// 234.754 us; speedup vs baseline: 1.1542x; 1.1542x over previous
//
#include <hip/hip_runtime.h>

#define N_ 16384
#define D_ 256
#define LOG2E 1.4426950408889634f
#define HEXP2(x) __builtin_amdgcn_exp2f(x)

typedef __attribute__((ext_vector_type(8))) short short8;
typedef __attribute__((ext_vector_type(16))) float floatx16;

typedef __attribute__((address_space(1))) const unsigned int gu32_t;
typedef __attribute__((address_space(3))) unsigned int lu32_t;

__device__ __forceinline__ void async16(const void* g, void* l) {
  __builtin_amdgcn_global_load_lds((gu32_t*)g, (lu32_t*)l, 16, 0, 0);
}

__device__ __forceinline__ unsigned short f2bf(float x) {
  unsigned int u = __float_as_uint(x);
  u += 0x7fffu + ((u >> 16) & 1u);
  return (unsigned short)(u >> 16);
}

__device__ __forceinline__ float max3f(float a, float b, float c) {
  return fmaxf(fmaxf(a, b), c);  // clang folds to v_max3_f32
}

// ---------------- prep: fp32 -> bf16 packed (write-coalesced) + fused exact diag ----------------
// (passed rounds 1, 2, 5, 8, 10, 12)
__global__ void prep_pack(const float* __restrict__ img, const float* __restrict__ txt,
                          const float* __restrict__ ls, short* __restrict__ PA,
                          short* __restrict__ PB, float* __restrict__ diag2,
                          float* __restrict__ out) {
  const int tid = threadIdx.x;
  const int t = blockIdx.x * 1024 + tid;
  const int m = tid & 31, h = (tid >> 5) & 1, ks = (tid >> 6) & 15;
  const int G = blockIdx.x;
  const int row = G * 32 + m, col = ks * 16 + h * 8;
  const float s2 = ls[0] * LOG2E;
  const float4* sa = (const float4*)(img + (size_t)row * D_ + col);
  const float4* sb = (const float4*)(txt + (size_t)row * D_ + col);
  float4 a0 = sa[0], a1 = sa[1];
  float4 b0 = sb[0], b1 = sb[1];
  short8 oa, ob;
  oa[0] = (short)f2bf(a0.x * s2); oa[1] = (short)f2bf(a0.y * s2);
  oa[2] = (short)f2bf(a0.z * s2); oa[3] = (short)f2bf(a0.w * s2);
  oa[4] = (short)f2bf(a1.x * s2); oa[5] = (short)f2bf(a1.y * s2);
  oa[6] = (short)f2bf(a1.z * s2); oa[7] = (short)f2bf(a1.w * s2);
  ob[0] = (short)f2bf(b0.x); ob[1] = (short)f2bf(b0.y);
  ob[2] = (short)f2bf(b0.z); ob[3] = (short)f2bf(b0.w);
  ob[4] = (short)f2bf(b1.x); ob[5] = (short)f2bf(b1.y);
  ob[6] = (short)f2bf(b1.z); ob[7] = (short)f2bf(b1.w);
  ((short8*)PA)[t] = oa;
  ((short8*)PB)[t] = ob;

  float d = a0.x * b0.x + a0.y * b0.y + a0.z * b0.z + a0.w * b0.w
          + a1.x * b1.x + a1.y * b1.y + a1.z * b1.z + a1.w * b1.w;
  __shared__ float red[32][33];
  red[tid >> 5][m] = d;
  __syncthreads();
  if (tid < 32) {
    float s = 0.f;
    #pragma unroll
    for (int q = 0; q < 32; ++q) s += red[q][tid];
    diag2[G * 32 + tid] = s * s2;  // log2-domain scaled diagonal
  }
  if (t == 0) out[0] = 0.f;
}

// ---------------- gemm + stats: A-in-registers, continuous B pipeline ----------------
// SESSION-BEST GREEN (r12, gemm 167us / total 240.8us). r8 structure + register-
// local micro-opts:
//  * acc zero-init deleted (zv as C operand of each tile's first MFMA quartet)
//  * max3-shaped max tree (v_max3_f32 folding)
//  * 4-chain row sum in phase2
//  * r10-proven closing-barrier removal (9 barriers/tile)
// MEASURED LEDGER (do not retry):
//  * 2-barrier phase discipline is OPTIMAL: removal neutral (r10), 4-buffer
//    single-barrier regresses -23% (r13: DMA issue de-clustering lengthens
//    vmcnt waits). Butterfly+rowbuf2 row path regresses (r6, r13).
//  * OCCUPANCY PINNED 2 blocks/CU: launch_bounds(256,3) spills (r9: VGPR 84,
//    FETCH 412MB); 32x128 tiles regress even with lower reg use (r1, r11).
//  * setprio neg (r2); XCD swizzle null (r7); prep LDS-transpose null (r7);
//    per-wave-private staging neg (r6).
// The ~36% MfmaUtil is this 2-wave/SIMD lockstep structure's ceiling; beyond it
// requires the 8-wave 256-tile deep-pipeline rewrite (different kernel family).
__global__ __launch_bounds__(256, 2)
void gemm_stats(const short* __restrict__ PA, const short* __restrict__ PB,
                float2* __restrict__ pR, float2* __restrict__ pC) {
  __shared__ __align__(16) char smem[73728];
  // [0,32768): B staging dbuf (2 x 16KB, 16 frags x 1KB each)
  // [32768,71680): rowbuf f32 [wr*64+slot][76] (38912 B)
  // [71680,73728): colbuf float2[2][128]
  float* rowbuf  = (float*)(smem + 32768);
  float2* colbuf = (float2*)(smem + 71680);

  const int tid = threadIdx.x, lane = tid & 63, wv = tid >> 6;
  const int wr = wv >> 1, wc = wv & 1;
  const int m = lane & 31, h = lane >> 5;
  const int stripe = blockIdx.x, by = blockIdx.y;

  // ---- A panel into registers: rows stripe*128 + wr*64 .. +64, all K
  short8 areg[2][16];
  #pragma unroll
  for (int g = 0; g < 2; ++g)
    #pragma unroll
    for (int ks = 0; ks < 16; ++ks)
      areg[g][ks] = *(const short8*)(PA +
          ((size_t)((stripe * 4 + wr * 2 + g) * 16 + ks)) * 512 + lane * 8);
  asm volatile("s_waitcnt vmcnt(0)" ::: "memory");

  floatx16 acc[2][2];
  floatx16 zv;
  #pragma unroll
  for (int r = 0; r < 16; ++r) zv[r] = 0.f;

  // stage chunk (jj2, c2) -> buffer bufsel. Wave wv stages ks-slice wv for 4 ct frags.
  auto issue = [&](int jj2, int c2, int bufsel) {
    const short* base = PB + ((size_t)((by * 64 + jj2 * 4) * 16) + c2 * 4 + wv) * 512 + lane * 8;
    char* dst = smem + bufsel * 16384 + wv * 1024;
    #pragma unroll
    for (int ct = 0; ct < 4; ++ct)
      async16(base + (size_t)ct * 8192, dst + ct * 4096);
  };
  auto compute = [&](int c, int bufsel, bool first) {
    char* base = smem + bufsel * 16384 + lane * 16;
    #pragma unroll
    for (int ksl = 0; ksl < 4; ++ksl) {
      short8 b0 = *(const short8*)(base + ((wc * 2 + 0) * 4 + ksl) * 1024);
      short8 b1 = *(const short8*)(base + ((wc * 2 + 1) * 4 + ksl) * 1024);
      int ks = c * 4 + ksl;  // compile-time under unroll
      if (first && ksl == 0) {
        acc[0][0] = __builtin_amdgcn_mfma_f32_32x32x16_bf16(areg[0][ks], b0, zv, 0, 0, 0);
        acc[1][0] = __builtin_amdgcn_mfma_f32_32x32x16_bf16(areg[1][ks], b0, zv, 0, 0, 0);
        acc[0][1] = __builtin_amdgcn_mfma_f32_32x32x16_bf16(areg[0][ks], b1, zv, 0, 0, 0);
        acc[1][1] = __builtin_amdgcn_mfma_f32_32x32x16_bf16(areg[1][ks], b1, zv, 0, 0, 0);
      } else {
        acc[0][0] = __builtin_amdgcn_mfma_f32_32x32x16_bf16(areg[0][ks], b0, acc[0][0], 0, 0, 0);
        acc[1][0] = __builtin_amdgcn_mfma_f32_32x32x16_bf16(areg[1][ks], b0, acc[1][0], 0, 0, 0);
        acc[0][1] = __builtin_amdgcn_mfma_f32_32x32x16_bf16(areg[0][ks], b1, acc[0][1], 0, 0, 0);
        acc[1][1] = __builtin_amdgcn_mfma_f32_32x32x16_bf16(areg[1][ks], b1, acc[1][1], 0, 0, 0);
      }
    }
  };

  issue(0, 0, 0);
  issue(0, 1, 1);

  float Mr = -3.0e38f, Sr = 0.f;  // row LSE state: row = stripe*128 + wr*64 + wc*32 + m

  for (int jj = 0; jj < 16; ++jj) {
    #pragma unroll
    for (int c = 0; c < 4; ++c) {
      if (jj == 15 && c == 3) { asm volatile("s_waitcnt vmcnt(0)" ::: "memory"); }
      else                    { asm volatile("s_waitcnt vmcnt(4)" ::: "memory"); }
      __builtin_amdgcn_s_barrier();
      asm volatile("" ::: "memory");
      compute(c, c & 1, c == 0);
      asm volatile("" ::: "memory");
      __builtin_amdgcn_s_barrier();
      asm volatile("" ::: "memory");
      int nc = c + 2;
      int jj2 = jj + (nc >> 2);
      if (jj2 < 16) issue(jj2, nc & 3, nc & 1);
    }

    // ---- stats. acc[rt][ctl][reg]: row(in tile) = wr*64+rt*32+(reg&3)+8*(reg>>2)+4*h
    //                                col(in tile) = wc*64+ctl*32+m
    // max3-shaped reduce (v_max3_f32): 16 values -> 8 ops, short chains
    float vm[4];
    #pragma unroll
    for (int q = 0; q < 4; ++q) {
      const floatx16& a = acc[q >> 1][q & 1];
      float t0 = max3f(a[0],  a[1],  a[2]);
      float t1 = max3f(a[3],  a[4],  a[5]);
      float t2 = max3f(a[6],  a[7],  a[8]);
      float t3 = max3f(a[9],  a[10], a[11]);
      float t4 = max3f(a[12], a[13], a[14]);
      vm[q] = fmaxf(max3f(t0, t1, a[15]), max3f(t2, t3, t4));
    }
    float v = fmaxf(max3f(vm[0], vm[1], vm[2]), vm[3]);
    #pragma unroll
    for (int off = 1; off < 64; off <<= 1) v = fmaxf(v, __shfl_xor(v, off));
    float msub = v - 96.f;

    #pragma unroll
    for (int rt = 0; rt < 2; ++rt)
      #pragma unroll
      for (int ctl = 0; ctl < 2; ++ctl)
        #pragma unroll
        for (int r = 0; r < 16; ++r) acc[rt][ctl][r] = HEXP2(acc[rt][ctl][r] - msub);

    // col partials: sum over 64 rows of wave tile (reg-local + xor32)
    #pragma unroll
    for (int ctl = 0; ctl < 2; ++ctl) {
      float cp0 = 0.f, cp1 = 0.f;
      #pragma unroll
      for (int r = 0; r < 8; ++r) {
        cp0 += acc[0][ctl][r] + acc[1][ctl][r];
        cp1 += acc[0][ctl][r + 8] + acc[1][ctl][r + 8];
      }
      float cp = cp0 + cp1;
      cp += __shfl_xor(cp, 32);
      if (h == 0) colbuf[wr * 128 + wc * 64 + ctl * 32 + m] = make_float2(msub, cp);
    }

    // row partials: ctl-add, pack 4 rows -> float4, rowbuf[(wr*64+slot)*76 + row]
    #pragma unroll
    for (int rt = 0; rt < 2; ++rt)
      #pragma unroll
      for (int rq = 0; rq < 4; ++rq) {
        float4 rp;
        rp.x = acc[rt][0][rq * 4 + 0] + acc[rt][1][rq * 4 + 0];
        rp.y = acc[rt][0][rq * 4 + 1] + acc[rt][1][rq * 4 + 1];
        rp.z = acc[rt][0][rq * 4 + 2] + acc[rt][1][rq * 4 + 2];
        rp.w = acc[rt][0][rq * 4 + 3] + acc[rt][1][rq * 4 + 3];
        *(float4*)&rowbuf[(wr * 64 + wc * 32 + m) * 76 + rt * 32 + rq * 8 + h * 4] = rp;
      }
    asm volatile("s_waitcnt lgkmcnt(0)" ::: "memory");
    __builtin_amdgcn_s_barrier();
    asm volatile("" ::: "memory");

    // phase2 rows: 4 parallel chains (was one 32-deep dependent chain)
    {
      float s0 = 0.f, s1 = 0.f, s2 = 0.f, s3 = 0.f;
      #pragma unroll
      for (int k = 0; k < 8; ++k) {
        s0 += rowbuf[(wr * 64 + h * 32 + k)      * 76 + wc * 32 + m];
        s1 += rowbuf[(wr * 64 + h * 32 + k + 8)  * 76 + wc * 32 + m];
        s2 += rowbuf[(wr * 64 + h * 32 + k + 16) * 76 + wc * 32 + m];
        s3 += rowbuf[(wr * 64 + h * 32 + k + 24) * 76 + wc * 32 + m];
      }
      float s = (s0 + s1) + (s2 + s3);
      s += __shfl_xor(s, 32);
      if (s > 0.f) {
        if (msub > Mr) { Sr = Sr * HEXP2(Mr - msub) + s; Mr = msub; }
        else           { Sr += s * HEXP2(msub - Mr); }
      }
    }
    // phase2 cols: merge wr=0/1 partials -> pC
    if (tid < 128) {
      float2 c0 = colbuf[tid], c1 = colbuf[128 + tid];
      float M = -3.0e38f, L = 0.f;
      if (c0.y > 0.f) { M = c0.x; L = c0.y; }
      if (c1.y > 0.f) {
        if (c1.x > M) { L = L * HEXP2(M - c1.x) + c1.y; M = c1.x; }
        else          { L += c1.y * HEXP2(c1.x - M); }
      }
      pC[(size_t)stripe * N_ + by * 2048 + jj * 128 + tid] = make_float2(M, L);
    }
    // (closing barrier removed -- r10-proven: next rowbuf/colbuf write is behind
    //  tile jj+1's 8 phase barriers)
  }

  if (h == 0)
    pR[(size_t)by * N_ + stripe * 128 + wr * 64 + wc * 32 + m] = make_float2(Mr, Sr);
}

// ---------------- merge v2: parallelized (passed rounds 8, 10, 12) ----------------
__global__ void merge_kernel(const float2* __restrict__ pR, const float2* __restrict__ pC,
                             const float* __restrict__ diag2, float* __restrict__ out) {
  auto mrg = [](float& M, float& L, float2 w) {
    if (w.y > 0.f) {
      if (w.x > M) { L = L * exp2f(M - w.x) + w.y; M = w.x; }
      else         { L += w.y * exp2f(w.x - M); }
    }
  };
  const int b = blockIdx.x, tid = threadIdx.x;
  float val = 0.f;

  if (b < 64) {
    int i = b * 256 + tid;
    float M = -3.0e38f, L = 0.f;
    #pragma unroll
    for (int g = 0; g < 8; ++g) mrg(M, L, pR[(size_t)g * N_ + i]);
    val = (M + log2f(fmaxf(L, 1e-45f))) - diag2[i];
  } else {
    int cb = b - 64;                 // 0..511
    int i = cb * 32 + (tid & 31);
    int s0 = (tid >> 5) * 16;
    float M = -3.0e38f, L = 0.f;
    #pragma unroll
    for (int k = 0; k < 16; ++k) mrg(M, L, pC[(size_t)(s0 + k) * N_ + i]);
    __shared__ float2 part[8][32];
    part[tid >> 5][tid & 31] = make_float2(M, L);
    __syncthreads();
    if (tid < 32) {
      float M2 = -3.0e38f, L2 = 0.f;
      #pragma unroll
      for (int q = 0; q < 8; ++q) mrg(M2, L2, part[q][tid]);
      val = (M2 + log2f(fmaxf(L2, 1e-45f))) - diag2[cb * 32 + tid];
    }
  }

  __shared__ float red[256];
  red[tid] = val;
  __syncthreads();
  #pragma unroll
  for (int s = 128; s > 0; s >>= 1) {
    if (tid < s) red[tid] += red[tid + s];
    __syncthreads();
  }
  if (tid == 0)
    atomicAdd(out, red[0] * (0.69314718055994531f / 32768.0f));  // ln2 / (2N)
}

// ---------------- launch ----------------
extern "C" void kernel_launch(void* const* d_in, const int* in_sizes, int n_in,
                              void* d_out, int out_size, void* d_ws, size_t ws_size,
                              hipStream_t stream) {
  const float* img = (const float*)d_in[0];
  const float* txt = (const float*)d_in[1];
  const float* ls  = (const float*)d_in[2];
  float* out = (float*)d_out;

  char* ws = (char*)d_ws;
  short* PA    = (short*)(ws);                 //  8 MB
  short* PB    = (short*)(ws + 8388608);       //  8 MB
  float* diag2 = (float*)(ws + 16777216);      //  64 KB
  float2* pR   = (float2*)(ws + 16843008);     //  1 MB  (8 x N)
  float2* pC   = (float2*)(ws + 17891584);     //  16 MB (128 x N)

  hipLaunchKernelGGL(prep_pack, dim3(512), dim3(1024), 0, stream, img, txt, ls, PA, PB, diag2, out);
  hipLaunchKernelGGL(gemm_stats, dim3(128, 8), dim3(256), 0, stream, PA, PB, pR, pC);
  hipLaunchKernelGGL(merge_kernel, dim3(576), dim3(256), 0, stream, pR, pC, diag2, out);
}